// Round 1
// baseline (448.436 us; speedup 1.0000x reference)
//
#include <hip/hip_runtime.h>
#include <hip/hip_bf16.h>
#include <hip/hip_fp16.h>

// R8: full_attn_mfma rewritten to cut LDS-pipe work (the measured bottleneck:
// MfmaUtil 15.6%, 9.4M LDS bank-conflict cycles, LDS-instr accounting ~85% of
// runtime):
//  - swapped QK^T (mfma(K,Q)) so each lane holds P for ONE query (its fr);
//    P never touches LDS: packed to f16 pairs and redistributed to the PV
//    A-fragment layout with 16 __shfl + 8 selects per q-tile (permutation
//    among the 4 same-fr lanes: src = fr + 16*((2*grp+h)&3), J = 2c+(grp>>1)).
//  - Ps buffer, both wave_barriers, 32 scalar P-writes and 4 P-reads per tile
//    deleted; LDS/block 27648 -> 18432.
//  - K-fragments and V-fragments hoisted out of the qt loop (they are
//    qt-invariant); phased so kf is dead before vf loads (VGPR ~155).
//  - denominator: lane-local accumulate, 2 shfl_xor reduce (16,32), final
//    per-query fetch via shfl.
// Everything else (win_attn, GEMMs, launch) identical to R7.

using f16 = _Float16;
typedef _Float16 f16x8 __attribute__((ext_vector_type(8)));
typedef _Float16 f16x2 __attribute__((ext_vector_type(2)));
typedef float    f32x4 __attribute__((ext_vector_type(4)));

__device__ inline void storeC(float* p, float v) { *p = v; }
__device__ inline void storeC(f16* p, float v)   { *p = (f16)v; }

// async 16B global -> LDS (dest = wave-uniform base + lane*16)
__device__ inline void async_cp16(const f16* g, f16* l) {
    __builtin_amdgcn_global_load_lds(
        (const __attribute__((address_space(1))) unsigned int*)g,
        (__attribute__((address_space(3))) unsigned int*)l,
        16, 0, 0);
}

// ---------------------------------------------------------------------------
// fp32 -> fp16 conversion, 8 elements/thread
// ---------------------------------------------------------------------------
__global__ __launch_bounds__(256) void f32_to_f16(
    const float* __restrict__ in, f16* __restrict__ out, int n)
{
    int i = (blockIdx.x * 256 + threadIdx.x) * 8;
    if (i >= n) return;
    float4 a = *(const float4*)(in + i);
    float4 b = *(const float4*)(in + i + 4);
    f16x8 h = { (f16)a.x, (f16)a.y, (f16)a.z, (f16)a.w,
                (f16)b.x, (f16)b.y, (f16)b.z, (f16)b.w };
    *(f16x8*)(out + i) = h;
}

// ---------------------------------------------------------------------------
// Wo[z] (512x512 f32) -> WoT[z] (512x512 f16), WoT[d][c] = Wo[c][d]
// ---------------------------------------------------------------------------
__global__ __launch_bounds__(256) void transpose_wo(
    const float* __restrict__ Wo, f16* __restrict__ WoT)
{
    __shared__ float t[32][33];
    const int z = blockIdx.z;
    const int bx = blockIdx.x * 32;
    const int by = blockIdx.y * 32;
    const int tx = threadIdx.x & 31;
    const int ty = threadIdx.x >> 5;
#pragma unroll
    for (int r = ty; r < 32; r += 8)
        t[r][tx] = Wo[(size_t)z * 262144 + (by + r) * 512 + bx + tx];
    __syncthreads();
#pragma unroll
    for (int r = ty; r < 32; r += 8)
        WoT[(size_t)z * 262144 + (bx + r) * 512 + by + tx] = (f16)t[tx][r];
}

// ---------------------------------------------------------------------------
// b'[o] = bf[o] + sum_j Wf[o][j] * bo_flat[j]   (one wave per o)
// ---------------------------------------------------------------------------
__global__ __launch_bounds__(256) void bias_fuse(
    const float* __restrict__ Wf, const float* __restrict__ bo,
    const float* __restrict__ bfv, float* __restrict__ bp)
{
    const int o = blockIdx.x * 4 + (threadIdx.x >> 6);
    const int lane = threadIdx.x & 63;
    float s = 0.f;
    for (int j = lane; j < 1536; j += 64) s += Wf[o * 1536 + j] * bo[j];
#pragma unroll
    for (int msk = 1; msk < 64; msk <<= 1) s += __shfl_xor(s, msk, 64);
    if (lane == 0) bp[o] = s + bfv[o];
}

// ---------------------------------------------------------------------------
// MFMA GEMM:  C[m,n] = sum_k A[m,k]*B[n,k] (+ bias[n])   (NT, fp16 in)
// z-batched via blockIdx.z with element strides azs/bzs/czs. bias nullable.
// ---------------------------------------------------------------------------
template <typename TC>
__global__ __launch_bounds__(256) void gemm_mfma_nt(
    const f16* __restrict__ A, int lda, long azs,
    const f16* __restrict__ B, int ldb, long bzs,
    const float* __restrict__ bias,
    TC* __restrict__ C, int ldc, long czs,
    int K)
{
    __shared__ __align__(16) f16 As[128 * 32];
    __shared__ __align__(16) f16 Bs[128 * 32];

    const int tid  = threadIdx.x;
    const int lane = tid & 63;
    const int wave = tid >> 6;
    const int wm = (wave >> 1) * 64;
    const int wn = (wave & 1) * 64;
    const int bm = blockIdx.y * 128;
    const int bn = blockIdx.x * 128;
    const int z  = blockIdx.z;

    const int srow = tid >> 2;
    const int scol = (tid & 3) * 8;

    const f16* Ag = A + (size_t)z * azs + (size_t)(bm + srow) * lda + scol;
    const f16* Bg = B + (size_t)z * bzs + (size_t)(bn + srow) * ldb + scol;
    f16* AsW = As + srow * 32 + scol;
    f16* BsW = Bs + srow * 32 + scol;

    f32x4 acc[4][4];
#pragma unroll
    for (int i = 0; i < 4; ++i)
#pragma unroll
        for (int j = 0; j < 4; ++j)
            acc[i][j] = (f32x4){0.f, 0.f, 0.f, 0.f};

    const int fr = lane & 15;
    const int fk = (lane >> 4) * 8;

    for (int k0 = 0; k0 < K; k0 += 32) {
        __syncthreads();
        async_cp16(Ag + k0, AsW);
        async_cp16(Ag + k0 + (size_t)64 * lda, AsW + 64 * 32);
        async_cp16(Bg + k0, BsW);
        async_cp16(Bg + k0 + (size_t)64 * ldb, BsW + 64 * 32);
        __syncthreads();

        f16x8 af[4], bfr[4];
#pragma unroll
        for (int i = 0; i < 4; ++i)
            af[i] = *(const f16x8*)&As[(wm + i * 16 + fr) * 32 + fk];
#pragma unroll
        for (int j = 0; j < 4; ++j)
            bfr[j] = *(const f16x8*)&Bs[(wn + j * 16 + fr) * 32 + fk];
#pragma unroll
        for (int i = 0; i < 4; ++i)
#pragma unroll
            for (int j = 0; j < 4; ++j)
                acc[i][j] = __builtin_amdgcn_mfma_f32_16x16x32_f16(
                    af[i], bfr[j], acc[i][j], 0, 0, 0);
    }

    const int cn  = lane & 15;
    const int cr4 = (lane >> 4) * 4;
#pragma unroll
    for (int i = 0; i < 4; ++i) {
#pragma unroll
        for (int j = 0; j < 4; ++j) {
            const int col = bn + wn + j * 16 + cn;
            const float bv = bias ? bias[col] : 0.f;
#pragma unroll
            for (int r = 0; r < 4; ++r) {
                const int row = bm + wm + i * 16 + cr4 + r;
                storeC(&C[(size_t)z * czs + (size_t)row * ldc + col],
                       acc[i][j][r] + bv);
            }
        }
    }
}

// ---------------------------------------------------------------------------
// Windowed causal attention via MFMA (unchanged from R7).
// ---------------------------------------------------------------------------
__global__ __launch_bounds__(256) void win_attn_mfma(
    const f16* __restrict__ qkv, f16* __restrict__ out, int w)
{
    __shared__ __align__(16) f16 Vs[4][64 * 40];   // per-wave [dim64][key32]
    __shared__ __align__(16) f16 Ps[4][16 * 40];   // per-wave [q16][key32]

    const int tid  = threadIdx.x;
    const int lane = tid & 63;
    const int wave = tid >> 6;
    const int b  = blockIdx.y;
    const int h  = blockIdx.z;
    const int q0 = (blockIdx.x * 4 + wave) * 16;
    const size_t bs = (size_t)b * 1024;

    const int fr  = lane & 15;
    const int grp = lane >> 4;
    const int fk8 = grp * 8;

    // Q A-frags, scaled by 1/8 * log2(e) so p = exp2(s)
    f16x8 aq[2];
    {
        const f16* qp = qkv + (bs + q0 + fr) * 1536 + h * 64 + fk8;
        aq[0] = *(const f16x8*)qp;
        aq[1] = *(const f16x8*)(qp + 32);
#pragma unroll
        for (int e = 0; e < 8; ++e) {
            aq[0][e] *= (f16)0.18033688;
            aq[1][e] *= (f16)0.18033688;
        }
    }

    // K B-frags, 2 groups of 16 keys (rows clamped; clamped keys get P=0)
    f16x8 bk[2][2];
#pragma unroll
    for (int g = 0; g < 2; ++g) {
        int krow = q0 - 16 + g * 16 + fr;
        int kcl  = krow < 0 ? 0 : krow;
        const f16* kp = qkv + (bs + kcl) * 1536 + 512 + h * 64 + fk8;
        bk[g][0] = *(const f16x8*)kp;
        bk[g][1] = *(const f16x8*)(kp + 32);
    }

    // stage V transposed into wave-private LDS: Vs[d][key], 32 keys
    {
        const int vk = lane & 31;
        const int vd = (lane >> 5) * 32;
        int vrow = q0 - 16 + vk;
        int vcl  = vrow < 0 ? 0 : vrow;
        const f16* vp = qkv + (bs + vcl) * 1536 + 1024 + h * 64 + vd;
        f16* vsw = Vs[wave];
#pragma unroll
        for (int t = 0; t < 4; ++t) {
            f16x8 vv = *(const f16x8*)(vp + t * 8);
#pragma unroll
            for (int e = 0; e < 8; ++e)
                vsw[(vd + t * 8 + e) * 40 + vk] = vv[e];
        }
    }

    // QK^T: 16q x 32keys, 4 MFMAs
    f32x4 s[2];
#pragma unroll
    for (int g = 0; g < 2; ++g) {
        f32x4 z = (f32x4){0.f, 0.f, 0.f, 0.f};
        z = __builtin_amdgcn_mfma_f32_16x16x32_f16(aq[0], bk[g][0], z, 0, 0, 0);
        s[g] = __builtin_amdgcn_mfma_f32_16x16x32_f16(aq[1], bk[g][1], z, 0, 0, 0);
    }

    // mask: 0 <= q-k < w AND absolute key position >= 0, then flat exp2
    float l[4] = {0.f, 0.f, 0.f, 0.f};
#pragma unroll
    for (int g = 0; g < 2; ++g) {
        const int kpos = q0 - 16 + g * 16 + fr;    // absolute key position
#pragma unroll
        for (int r = 0; r < 4; ++r) {
            const int diff = (grp * 4 + r) - (g * 16 + fr) + 16;   // q - k
            const bool ok = (diff >= 0) && (diff < w) && (kpos >= 0);
            float p = ok ? exp2f(fminf(s[g][r], 15.9f)) : 0.f;
            l[r] += p;
            Ps[wave][(grp * 4 + r) * 40 + g * 16 + fr] = (f16)p;
        }
    }

    __builtin_amdgcn_wave_barrier();   // wave-local LDS writes before reads

    // PV: O[16q][64d] = P(16x32) * V^T, 4 MFMAs (one K=32 contraction each)
    f16x8 pa = *(const f16x8*)&Ps[wave][fr * 40 + fk8];
    f32x4 acc[4];
#pragma unroll
    for (int j = 0; j < 4; ++j) {
        f16x8 bv = *(const f16x8*)&Vs[wave][(j * 16 + fr) * 40 + fk8];
        f32x4 z = (f32x4){0.f, 0.f, 0.f, 0.f};
        acc[j] = __builtin_amdgcn_mfma_f32_16x16x32_f16(pa, bv, z, 0, 0, 0);
    }

    // reduce l across the 16-lane group, write O
#pragma unroll
    for (int r = 0; r < 4; ++r)
#pragma unroll
        for (int msk = 1; msk < 16; msk <<= 1)
            l[r] += __shfl_xor(l[r], msk, 64);

#pragma unroll
    for (int j = 0; j < 4; ++j)
#pragma unroll
        for (int r = 0; r < 4; ++r) {
            const int q = q0 + grp * 4 + r;
            out[(bs + q) * 1536 + h * 64 + j * 16 + fr] = (f16)(acc[j][r] / l[r]);
        }
}

// ---------------------------------------------------------------------------
// Full attention, MFMA flash v4: swapped QK^T, register-resident P, hoisted
// K/V fragments, no Ps buffer.
// ---------------------------------------------------------------------------
__global__ __launch_bounds__(256) void full_attn_mfma(
    const f16* __restrict__ qkv, f16* __restrict__ out)
{
    __shared__ __align__(16) f16 Ks[64 * 72];   // [key][d]
    __shared__ __align__(16) f16 Vs[64 * 72];   // [d][key]

    const int tid  = threadIdx.x;
    const int lane = tid & 63;
    const int wave = tid >> 6;
    const int q0 = blockIdx.x * 128;
    const int b  = blockIdx.y;
    const int h  = blockIdx.z;
    const size_t bs = (size_t)b * 1024;

    const int fr  = lane & 15;
    const int grp = lane >> 4;
    const int fk8 = grp * 8;

    // P-exchange constants: lane (grp,fr) pulls from lane fr + 16*((2*grp+h)&3)
    // and selects dword J = 2c + (grp>>1), T = tt&1.
    const int jhi   = grp >> 1;
    const int psrc0 = fr + 16 * ((2 * grp) & 3);
    const int psrc1 = fr + 16 * ((2 * grp + 1) & 3);

    // Q B-frags (rows = queries), scaled by 1/8 * log2(e) so p = exp2(s)
    f16x8 aq[2][2];
#pragma unroll
    for (int qt = 0; qt < 2; ++qt) {
        const f16* qp = qkv + (bs + q0 + wave * 32 + qt * 16 + fr) * 1536
                        + h * 64 + fk8;
        aq[qt][0] = *(const f16x8*)qp;
        aq[qt][1] = *(const f16x8*)(qp + 32);
#pragma unroll
        for (int e = 0; e < 8; ++e) {
            aq[qt][0][e] *= (f16)0.18033688;
            aq[qt][1][e] *= (f16)0.18033688;
        }
    }

    float l[2] = {0.f, 0.f};
    f32x4 acc[2][4];
#pragma unroll
    for (int qt = 0; qt < 2; ++qt)
#pragma unroll
        for (int j = 0; j < 4; ++j)
            acc[qt][j] = (f32x4){0.f, 0.f, 0.f, 0.f};

    const int kr = tid >> 2, kc = (tid & 3) * 16;
    const int vk = tid & 63, vd = (tid >> 6) * 16;

    f16x8 ka, kb, va, vb;
    {
        const f16* kp = qkv + (bs + kr) * 1536 + 512 + h * 64 + kc;
        ka = *(const f16x8*)kp; kb = *(const f16x8*)(kp + 8);
        const f16* vp = qkv + (bs + vk) * 1536 + 1024 + h * 64 + vd;
        va = *(const f16x8*)vp; vb = *(const f16x8*)(vp + 8);
    }

    for (int k0 = 0; k0 < 1024; k0 += 64) {
        __syncthreads();
        *(f16x8*)&Ks[kr * 72 + kc]     = ka;
        *(f16x8*)&Ks[kr * 72 + kc + 8] = kb;
#pragma unroll
        for (int e = 0; e < 8; ++e) {
            Vs[(vd + e)     * 72 + vk] = va[e];
            Vs[(vd + 8 + e) * 72 + vk] = vb[e];
        }
        __syncthreads();

        if (k0 + 64 < 1024) {
            const f16* kp = qkv + (bs + k0 + 64 + kr) * 1536 + 512 + h * 64 + kc;
            ka = *(const f16x8*)kp; kb = *(const f16x8*)(kp + 8);
            const f16* vp = qkv + (bs + k0 + 64 + vk) * 1536 + 1024 + h * 64 + vd;
            va = *(const f16x8*)vp; vb = *(const f16x8*)(vp + 8);
        }

        // hoisted K fragments (qt-invariant): K[j*16+fr][c*32 + grp*8 + e]
        f16x8 kf[4][2];
#pragma unroll
        for (int j = 0; j < 4; ++j)
#pragma unroll
            for (int c = 0; c < 2; ++c)
                kf[j][c] = *(const f16x8*)&Ks[(j * 16 + fr) * 72 + c * 32 + fk8];

        // swapped QK^T for both q-tiles: s2[qt][j][r] = S[k=j*16+grp*4+r][q=fr]
        f32x4 s2[2][4];
#pragma unroll
        for (int qt = 0; qt < 2; ++qt)
#pragma unroll
            for (int j = 0; j < 4; ++j) {
                f32x4 z = (f32x4){0.f, 0.f, 0.f, 0.f};
                z = __builtin_amdgcn_mfma_f32_16x16x32_f16(
                        kf[j][0], aq[qt][0], z, 0, 0, 0);
                s2[qt][j] = __builtin_amdgcn_mfma_f32_16x16x32_f16(
                        kf[j][1], aq[qt][1], z, 0, 0, 0);
            }

        // exp2, pack to f16 pairs, redistribute to PV A-fragment layout:
        // lane (grp,fr) needs P[q=fr][k = c*32 + grp*8 + e]
        f16x8 paf[2][2];
#pragma unroll
        for (int qt = 0; qt < 2; ++qt) {
            unsigned int dw[4][2];
#pragma unroll
            for (int j = 0; j < 4; ++j) {
                float p0 = exp2f(fminf(s2[qt][j][0], 15.9f));
                float p1 = exp2f(fminf(s2[qt][j][1], 15.9f));
                float p2 = exp2f(fminf(s2[qt][j][2], 15.9f));
                float p3 = exp2f(fminf(s2[qt][j][3], 15.9f));
                l[qt] += (p0 + p1) + (p2 + p3);
                f16x2 h0 = { (f16)p0, (f16)p1 };
                f16x2 h1 = { (f16)p2, (f16)p3 };
                dw[j][0] = __builtin_bit_cast(unsigned int, h0);
                dw[j][1] = __builtin_bit_cast(unsigned int, h1);
            }

            unsigned int pdw[2][4];
#pragma unroll
            for (int tt = 0; tt < 4; ++tt) {
                const int T   = tt & 1;
                const int src = (tt & 2) ? psrc1 : psrc0;
                unsigned int x0 = (unsigned int)__shfl((int)dw[0][T], src, 64);
                unsigned int x1 = (unsigned int)__shfl((int)dw[1][T], src, 64);
                unsigned int x2 = (unsigned int)__shfl((int)dw[2][T], src, 64);
                unsigned int x3 = (unsigned int)__shfl((int)dw[3][T], src, 64);
                pdw[0][tt] = jhi ? x1 : x0;
                pdw[1][tt] = jhi ? x3 : x2;
            }
            union { unsigned int u[4]; f16x8 h; } cu;
#pragma unroll
            for (int c = 0; c < 2; ++c) {
                cu.u[0] = pdw[c][0]; cu.u[1] = pdw[c][1];
                cu.u[2] = pdw[c][2]; cu.u[3] = pdw[c][3];
                paf[qt][c] = cu.h;
            }
        }

        // hoisted V fragments (qt-invariant): V^T[j*16+fr][c*32 + grp*8 + e]
        f16x8 vf[4][2];
#pragma unroll
        for (int j = 0; j < 4; ++j)
#pragma unroll
            for (int c = 0; c < 2; ++c)
                vf[j][c] = *(const f16x8*)&Vs[(j * 16 + fr) * 72 + c * 32 + fk8];

#pragma unroll
        for (int qt = 0; qt < 2; ++qt)
#pragma unroll
            for (int j = 0; j < 4; ++j)
#pragma unroll
                for (int c = 0; c < 2; ++c)
                    acc[qt][j] = __builtin_amdgcn_mfma_f32_16x16x32_f16(
                        paf[qt][c], vf[j][c], acc[qt][j], 0, 0, 0);
    }

    // denominator: lane holds partial sum for query fr; reduce over the
    // 4 same-fr lanes, then fetch the value for output queries grp*4 + r
#pragma unroll
    for (int qt = 0; qt < 2; ++qt) {
        l[qt] += __shfl_xor(l[qt], 16, 64);
        l[qt] += __shfl_xor(l[qt], 32, 64);
    }

    float lr[2][4];
#pragma unroll
    for (int qt = 0; qt < 2; ++qt)
#pragma unroll
        for (int r = 0; r < 4; ++r)
            lr[qt][r] = __shfl(l[qt], grp * 4 + r, 64);

#pragma unroll
    for (int qt = 0; qt < 2; ++qt)
#pragma unroll
        for (int j = 0; j < 4; ++j)
#pragma unroll
            for (int r = 0; r < 4; ++r) {
                const int q = q0 + wave * 32 + qt * 16 + grp * 4 + r;
                out[(bs + q) * 1536 + h * 64 + j * 16 + fr] =
                    (f16)(acc[qt][j][r] / lr[qt][r]);
            }
}

// ---------------------------------------------------------------------------
// launch
// ---------------------------------------------------------------------------
extern "C" void kernel_launch(void* const* d_in, const int* in_sizes, int n_in,
                              void* d_out, int out_size, void* d_ws, size_t ws_size,
                              hipStream_t stream)
{
    const float* x    = (const float*)d_in[0];   // [16,1024,512]
    const float* Wqkv = (const float*)d_in[1];   // [3,1536,512]
    const float* bqkv = (const float*)d_in[2];   // [3,1536]
    const float* Wo   = (const float*)d_in[3];   // [3,512,512]
    const float* bo   = (const float*)d_in[4];   // [3,512] (flat 1536)
    const float* Wf   = (const float*)d_in[5];   // [512,1536]
    const float* bfin = (const float*)d_in[6];   // [512]
    float* out = (float*)d_out;                  // [16,1024,512] fp32

    char* ws = (char*)d_ws;
    f16*   qkvbuf   = (f16*)ws;                        // 16384x1536 (50,331,648)
    f16*   attn_cat = (f16*)(ws + 50331648);           // 16384x1536 (50,331,648)
    f16*   wfh      = (f16*)(ws + 100663296);          // 512x1536   (1,572,864)
    f16*   WoT      = (f16*)(ws + 102236160);          // 3x512x512  (1,572,864)
    f16*   Wfo      = (f16*)(ws + 103809024);          // 512x1536   (1,572,864)
    float* bp       = (float*)(ws + 105381888);        // 512        (2,048)

    f16* xh    = (f16*)d_out;                          // 8,388,608 el (16.8 MB)
    f16* wqkvh = (f16*)((char*)d_out + 16777216);      // 2,359,296 el (4.7 MB)

    f32_to_f16<<<dim3(4096), 256, 0, stream>>>(x,    xh,    8388608);
    f32_to_f16<<<dim3(1152), 256, 0, stream>>>(Wqkv, wqkvh, 2359296);
    f32_to_f16<<<dim3(384),  256, 0, stream>>>(Wf,   wfh,   786432);
    transpose_wo<<<dim3(16, 16, 3), 256, 0, stream>>>(Wo, WoT);

    // Wfo[z] = Wf[:, 512z:512z+512] @ Wo[z]
    gemm_mfma_nt<f16><<<dim3(4, 4, 3), 256, 0, stream>>>(
        wfh, 1536, 512, WoT, 512, 262144, nullptr, Wfo, 1536, 512, 512);

    // b' = bf + Wf @ bo_flat
    bias_fuse<<<dim3(128), 256, 0, stream>>>(Wf, bo, bfin, bp);

    for (int i = 0; i < 3; ++i) {
        // qkv_i = x @ Wqkv[i]^T + bqkv[i]  -> [16384,1536] f16
        gemm_mfma_nt<f16><<<dim3(12, 128, 1), 256, 0, stream>>>(
            xh, 512, 0, wqkvh + (size_t)i * 786432, 512, 0, bqkv + i * 1536,
            qkvbuf, 1536, 0, 512);

        if (i == 0)
            win_attn_mfma<<<dim3(16, 16, 8), 256, 0, stream>>>(
                qkvbuf, attn_cat + 0 * 512, 5);
        else if (i == 1)
            win_attn_mfma<<<dim3(16, 16, 8), 256, 0, stream>>>(
                qkvbuf, attn_cat + 1 * 512, 10);
        else
            full_attn_mfma<<<dim3(8, 16, 8), 256, 0, stream>>>(
                qkvbuf, attn_cat + 2 * 512);
    }

    // out = attn_cat @ Wfo^T + b'  (fp32 out), M=16384 N=512 K=1536
    gemm_mfma_nt<float><<<dim3(4, 128, 1), 256, 0, stream>>>(
        attn_cat, 1536, 0, Wfo, 1536, 0, bp, out, 512, 0, 1536);
}

// Round 2
// 426.318 us; speedup vs baseline: 1.0519x; 1.0519x over previous
//
#include <hip/hip_runtime.h>
#include <hip/hip_bf16.h>
#include <hip/hip_fp16.h>

// R9: full_attn_mfma v5 — move work OFF the LDS pipe (R8 lesson: bpermute is
// an LDS op; swapping Ps-LDS for shuffles was LDS-neutral, dur unchanged).
//  - permlane32_swap + permlane16_swap (VALU) replace all 32 ds_bpermute per
//    tile AND the 16 cndmasks: P32 then P16 on (X=dw[2c][T], Y=dw[2c+1][T])
//    yields exactly O_h0=[x0,x2,y0,y2], O_h1=[x1,x3,y1,y3] = the two output
//    dwords of R8's verified shuffle spec.
//  - double-buffered Ks/Vs, ONE __syncthreads per tile (write t+1 -> buf^1
//    while computing t from buf; barrier at loop top certifies prior reads).
//  - V staging re-partitioned: thread holds a key-PAIR x 8 d's, writes
//    8 x ds_write_b32 (f16x2) instead of 16 x ds_write_b16 (conflict-free).
//  - denominator l via MFMA with all-ones B-fragment: C[q][n] = l[q] for all
//    n, landing in exactly the lane/reg the epilogue needs; kills 32 VALU
//    adds/tile and the end shuffle-reduction.
//  - __launch_bounds__(256,4) to keep VGPR<=128 (4 blocks/CU co-resident).
// win_attn, GEMMs, launch unchanged from R8.

using f16 = _Float16;
typedef _Float16 f16x8 __attribute__((ext_vector_type(8)));
typedef _Float16 f16x2 __attribute__((ext_vector_type(2)));
typedef float    f32x4 __attribute__((ext_vector_type(4)));

__device__ inline void storeC(float* p, float v) { *p = v; }
__device__ inline void storeC(f16* p, float v)   { *p = (f16)v; }

// async 16B global -> LDS (dest = wave-uniform base + lane*16)
__device__ inline void async_cp16(const f16* g, f16* l) {
    __builtin_amdgcn_global_load_lds(
        (const __attribute__((address_space(1))) unsigned int*)g,
        (__attribute__((address_space(3))) unsigned int*)l,
        16, 0, 0);
}

// ---------------------------------------------------------------------------
// fp32 -> fp16 conversion, 8 elements/thread
// ---------------------------------------------------------------------------
__global__ __launch_bounds__(256) void f32_to_f16(
    const float* __restrict__ in, f16* __restrict__ out, int n)
{
    int i = (blockIdx.x * 256 + threadIdx.x) * 8;
    if (i >= n) return;
    float4 a = *(const float4*)(in + i);
    float4 b = *(const float4*)(in + i + 4);
    f16x8 h = { (f16)a.x, (f16)a.y, (f16)a.z, (f16)a.w,
                (f16)b.x, (f16)b.y, (f16)b.z, (f16)b.w };
    *(f16x8*)(out + i) = h;
}

// ---------------------------------------------------------------------------
// Wo[z] (512x512 f32) -> WoT[z] (512x512 f16), WoT[d][c] = Wo[c][d]
// ---------------------------------------------------------------------------
__global__ __launch_bounds__(256) void transpose_wo(
    const float* __restrict__ Wo, f16* __restrict__ WoT)
{
    __shared__ float t[32][33];
    const int z = blockIdx.z;
    const int bx = blockIdx.x * 32;
    const int by = blockIdx.y * 32;
    const int tx = threadIdx.x & 31;
    const int ty = threadIdx.x >> 5;
#pragma unroll
    for (int r = ty; r < 32; r += 8)
        t[r][tx] = Wo[(size_t)z * 262144 + (by + r) * 512 + bx + tx];
    __syncthreads();
#pragma unroll
    for (int r = ty; r < 32; r += 8)
        WoT[(size_t)z * 262144 + (bx + r) * 512 + by + tx] = (f16)t[tx][r];
}

// ---------------------------------------------------------------------------
// b'[o] = bf[o] + sum_j Wf[o][j] * bo_flat[j]   (one wave per o)
// ---------------------------------------------------------------------------
__global__ __launch_bounds__(256) void bias_fuse(
    const float* __restrict__ Wf, const float* __restrict__ bo,
    const float* __restrict__ bfv, float* __restrict__ bp)
{
    const int o = blockIdx.x * 4 + (threadIdx.x >> 6);
    const int lane = threadIdx.x & 63;
    float s = 0.f;
    for (int j = lane; j < 1536; j += 64) s += Wf[o * 1536 + j] * bo[j];
#pragma unroll
    for (int msk = 1; msk < 64; msk <<= 1) s += __shfl_xor(s, msk, 64);
    if (lane == 0) bp[o] = s + bfv[o];
}

// ---------------------------------------------------------------------------
// MFMA GEMM:  C[m,n] = sum_k A[m,k]*B[n,k] (+ bias[n])   (NT, fp16 in)
// z-batched via blockIdx.z with element strides azs/bzs/czs. bias nullable.
// ---------------------------------------------------------------------------
template <typename TC>
__global__ __launch_bounds__(256) void gemm_mfma_nt(
    const f16* __restrict__ A, int lda, long azs,
    const f16* __restrict__ B, int ldb, long bzs,
    const float* __restrict__ bias,
    TC* __restrict__ C, int ldc, long czs,
    int K)
{
    __shared__ __align__(16) f16 As[128 * 32];
    __shared__ __align__(16) f16 Bs[128 * 32];

    const int tid  = threadIdx.x;
    const int lane = tid & 63;
    const int wave = tid >> 6;
    const int wm = (wave >> 1) * 64;
    const int wn = (wave & 1) * 64;
    const int bm = blockIdx.y * 128;
    const int bn = blockIdx.x * 128;
    const int z  = blockIdx.z;

    const int srow = tid >> 2;
    const int scol = (tid & 3) * 8;

    const f16* Ag = A + (size_t)z * azs + (size_t)(bm + srow) * lda + scol;
    const f16* Bg = B + (size_t)z * bzs + (size_t)(bn + srow) * ldb + scol;
    f16* AsW = As + srow * 32 + scol;
    f16* BsW = Bs + srow * 32 + scol;

    f32x4 acc[4][4];
#pragma unroll
    for (int i = 0; i < 4; ++i)
#pragma unroll
        for (int j = 0; j < 4; ++j)
            acc[i][j] = (f32x4){0.f, 0.f, 0.f, 0.f};

    const int fr = lane & 15;
    const int fk = (lane >> 4) * 8;

    for (int k0 = 0; k0 < K; k0 += 32) {
        __syncthreads();
        async_cp16(Ag + k0, AsW);
        async_cp16(Ag + k0 + (size_t)64 * lda, AsW + 64 * 32);
        async_cp16(Bg + k0, BsW);
        async_cp16(Bg + k0 + (size_t)64 * ldb, BsW + 64 * 32);
        __syncthreads();

        f16x8 af[4], bfr[4];
#pragma unroll
        for (int i = 0; i < 4; ++i)
            af[i] = *(const f16x8*)&As[(wm + i * 16 + fr) * 32 + fk];
#pragma unroll
        for (int j = 0; j < 4; ++j)
            bfr[j] = *(const f16x8*)&Bs[(wn + j * 16 + fr) * 32 + fk];
#pragma unroll
        for (int i = 0; i < 4; ++i)
#pragma unroll
            for (int j = 0; j < 4; ++j)
                acc[i][j] = __builtin_amdgcn_mfma_f32_16x16x32_f16(
                    af[i], bfr[j], acc[i][j], 0, 0, 0);
    }

    const int cn  = lane & 15;
    const int cr4 = (lane >> 4) * 4;
#pragma unroll
    for (int i = 0; i < 4; ++i) {
#pragma unroll
        for (int j = 0; j < 4; ++j) {
            const int col = bn + wn + j * 16 + cn;
            const float bv = bias ? bias[col] : 0.f;
#pragma unroll
            for (int r = 0; r < 4; ++r) {
                const int row = bm + wm + i * 16 + cr4 + r;
                storeC(&C[(size_t)z * czs + (size_t)row * ldc + col],
                       acc[i][j][r] + bv);
            }
        }
    }
}

// ---------------------------------------------------------------------------
// Windowed causal attention via MFMA (unchanged from R8).
// ---------------------------------------------------------------------------
__global__ __launch_bounds__(256) void win_attn_mfma(
    const f16* __restrict__ qkv, f16* __restrict__ out, int w)
{
    __shared__ __align__(16) f16 Vs[4][64 * 40];   // per-wave [dim64][key32]
    __shared__ __align__(16) f16 Ps[4][16 * 40];   // per-wave [q16][key32]

    const int tid  = threadIdx.x;
    const int lane = tid & 63;
    const int wave = tid >> 6;
    const int b  = blockIdx.y;
    const int h  = blockIdx.z;
    const int q0 = (blockIdx.x * 4 + wave) * 16;
    const size_t bs = (size_t)b * 1024;

    const int fr  = lane & 15;
    const int grp = lane >> 4;
    const int fk8 = grp * 8;

    // Q A-frags, scaled by 1/8 * log2(e) so p = exp2(s)
    f16x8 aq[2];
    {
        const f16* qp = qkv + (bs + q0 + fr) * 1536 + h * 64 + fk8;
        aq[0] = *(const f16x8*)qp;
        aq[1] = *(const f16x8*)(qp + 32);
#pragma unroll
        for (int e = 0; e < 8; ++e) {
            aq[0][e] *= (f16)0.18033688;
            aq[1][e] *= (f16)0.18033688;
        }
    }

    // K B-frags, 2 groups of 16 keys (rows clamped; clamped keys get P=0)
    f16x8 bk[2][2];
#pragma unroll
    for (int g = 0; g < 2; ++g) {
        int krow = q0 - 16 + g * 16 + fr;
        int kcl  = krow < 0 ? 0 : krow;
        const f16* kp = qkv + (bs + kcl) * 1536 + 512 + h * 64 + fk8;
        bk[g][0] = *(const f16x8*)kp;
        bk[g][1] = *(const f16x8*)(kp + 32);
    }

    // stage V transposed into wave-private LDS: Vs[d][key], 32 keys
    {
        const int vk = lane & 31;
        const int vd = (lane >> 5) * 32;
        int vrow = q0 - 16 + vk;
        int vcl  = vrow < 0 ? 0 : vrow;
        const f16* vp = qkv + (bs + vcl) * 1536 + 1024 + h * 64 + vd;
        f16* vsw = Vs[wave];
#pragma unroll
        for (int t = 0; t < 4; ++t) {
            f16x8 vv = *(const f16x8*)(vp + t * 8);
#pragma unroll
            for (int e = 0; e < 8; ++e)
                vsw[(vd + t * 8 + e) * 40 + vk] = vv[e];
        }
    }

    // QK^T: 16q x 32keys, 4 MFMAs
    f32x4 s[2];
#pragma unroll
    for (int g = 0; g < 2; ++g) {
        f32x4 z = (f32x4){0.f, 0.f, 0.f, 0.f};
        z = __builtin_amdgcn_mfma_f32_16x16x32_f16(aq[0], bk[g][0], z, 0, 0, 0);
        s[g] = __builtin_amdgcn_mfma_f32_16x16x32_f16(aq[1], bk[g][1], z, 0, 0, 0);
    }

    // mask: 0 <= q-k < w AND absolute key position >= 0, then flat exp2
    float l[4] = {0.f, 0.f, 0.f, 0.f};
#pragma unroll
    for (int g = 0; g < 2; ++g) {
        const int kpos = q0 - 16 + g * 16 + fr;    // absolute key position
#pragma unroll
        for (int r = 0; r < 4; ++r) {
            const int diff = (grp * 4 + r) - (g * 16 + fr) + 16;   // q - k
            const bool ok = (diff >= 0) && (diff < w) && (kpos >= 0);
            float p = ok ? exp2f(fminf(s[g][r], 15.9f)) : 0.f;
            l[r] += p;
            Ps[wave][(grp * 4 + r) * 40 + g * 16 + fr] = (f16)p;
        }
    }

    __builtin_amdgcn_wave_barrier();   // wave-local LDS writes before reads

    // PV: O[16q][64d] = P(16x32) * V^T, 4 MFMAs (one K=32 contraction each)
    f16x8 pa = *(const f16x8*)&Ps[wave][fr * 40 + fk8];
    f32x4 acc[4];
#pragma unroll
    for (int j = 0; j < 4; ++j) {
        f16x8 bv = *(const f16x8*)&Vs[wave][(j * 16 + fr) * 40 + fk8];
        f32x4 z = (f32x4){0.f, 0.f, 0.f, 0.f};
        acc[j] = __builtin_amdgcn_mfma_f32_16x16x32_f16(pa, bv, z, 0, 0, 0);
    }

    // reduce l across the 16-lane group, write O
#pragma unroll
    for (int r = 0; r < 4; ++r)
#pragma unroll
        for (int msk = 1; msk < 16; msk <<= 1)
            l[r] += __shfl_xor(l[r], msk, 64);

#pragma unroll
    for (int j = 0; j < 4; ++j)
#pragma unroll
        for (int r = 0; r < 4; ++r) {
            const int q = q0 + grp * 4 + r;
            out[(bs + q) * 1536 + h * 64 + j * 16 + fr] = (f16)(acc[j][r] / l[r]);
        }
}

// ---------------------------------------------------------------------------
// Full attention, MFMA flash v5: swapped QK^T, register P via permlane swaps,
// double-buffered K/V (1 barrier/tile), paired V scatter, l via ones-MFMA.
// ---------------------------------------------------------------------------
__global__ __launch_bounds__(256, 4) void full_attn_mfma(
    const f16* __restrict__ qkv, f16* __restrict__ out)
{
    __shared__ __align__(16) f16 Ks[2][64 * 72];   // [key][d]
    __shared__ __align__(16) f16 Vs[2][64 * 72];   // [d][key]

    const int tid  = threadIdx.x;
    const int lane = tid & 63;
    const int wave = tid >> 6;
    const int q0 = blockIdx.x * 128;
    const int b  = blockIdx.y;
    const int h  = blockIdx.z;
    const size_t bs = (size_t)b * 1024;

    const int fr  = lane & 15;
    const int grp = lane >> 4;
    const int fk8 = grp * 8;

    // Q B-frags (rows = queries), scaled by 1/8 * log2(e) so p = exp2(s)
    f16x8 aq[2][2];
#pragma unroll
    for (int qt = 0; qt < 2; ++qt) {
        const f16* qp = qkv + (bs + q0 + wave * 32 + qt * 16 + fr) * 1536
                        + h * 64 + fk8;
        aq[qt][0] = *(const f16x8*)qp;
        aq[qt][1] = *(const f16x8*)(qp + 32);
#pragma unroll
        for (int e = 0; e < 8; ++e) {
            aq[qt][0][e] *= (f16)0.18033688;
            aq[qt][1][e] *= (f16)0.18033688;
        }
    }

    // all-ones B-fragment for the l-MFMA (C[q][n] = sum_k P[q][k])
    f16x8 onesf;
#pragma unroll
    for (int e = 0; e < 8; ++e) onesf[e] = (f16)1.0f;

    const f32x4 fz = (f32x4){0.f, 0.f, 0.f, 0.f};
    f32x4 lacc[2] = {fz, fz};
    f32x4 acc[2][4];
#pragma unroll
    for (int qt = 0; qt < 2; ++qt)
#pragma unroll
        for (int j = 0; j < 4; ++j)
            acc[qt][j] = fz;

    // staging partitions: K by (row, 32B col chunk); V by (key-pair, 8-col block)
    const int kr = tid >> 2, kc = (tid & 3) * 16;
    const int kp = (tid & 31) * 2, cb = (tid >> 5) * 8;

    const f16* kgp = qkv + (bs + kr) * 1536 + 512 + h * 64 + kc;
    const f16* vgp = qkv + (bs + kp) * 1536 + 1024 + h * 64 + cb;

    f16x8 ka, kb, va, vb;
    // load tile 0
    ka = *(const f16x8*)kgp; kb = *(const f16x8*)(kgp + 8);
    va = *(const f16x8*)vgp; vb = *(const f16x8*)(vgp + 1536);

    // stage tile 0 -> buf 0 (ordered before first compute by iter-0 barrier)
    {
        f16* ks = &Ks[0][kr * 72 + kc];
        *(f16x8*)ks = ka; *(f16x8*)(ks + 8) = kb;
        f16* vs = &Vs[0][kp];
#pragma unroll
        for (int e = 0; e < 8; ++e) {
            f16x2 pr = { va[e], vb[e] };
            *(f16x2*)&vs[(cb + e) * 72] = pr;
        }
    }
    // load tile 1
    kgp += 64 * 1536; vgp += 64 * 1536;
    ka = *(const f16x8*)kgp; kb = *(const f16x8*)(kgp + 8);
    va = *(const f16x8*)vgp; vb = *(const f16x8*)(vgp + 1536);

    for (int t = 0; t < 16; ++t) {
        __syncthreads();   // certifies: buf[p^1] reads (tile t-1) drained,
                           // and stage of tile t (into buf[p]) visible
        const int p = t & 1;

        if (t + 1 < 16) {
            // stage tile t+1 -> buf[p^1]
            f16* ks = &Ks[p ^ 1][kr * 72 + kc];
            *(f16x8*)ks = ka; *(f16x8*)(ks + 8) = kb;
            f16* vs = &Vs[p ^ 1][kp];
#pragma unroll
            for (int e = 0; e < 8; ++e) {
                f16x2 pr = { va[e], vb[e] };
                *(f16x2*)&vs[(cb + e) * 72] = pr;
            }
            if (t + 2 < 16) {
                kgp += 64 * 1536; vgp += 64 * 1536;
                ka = *(const f16x8*)kgp; kb = *(const f16x8*)(kgp + 8);
                va = *(const f16x8*)vgp; vb = *(const f16x8*)(vgp + 1536);
            }
        }

        // hoisted K fragments (qt-invariant): K[j*16+fr][c*32 + grp*8 + e]
        f16x8 kf[4][2];
#pragma unroll
        for (int j = 0; j < 4; ++j)
#pragma unroll
            for (int c = 0; c < 2; ++c)
                kf[j][c] = *(const f16x8*)&Ks[p][(j * 16 + fr) * 72 + c * 32 + fk8];

        // per q-tile: swapped QK^T -> softmax -> permlane redistribute -> l-MFMA
        f16x8 paf[2][2];
#pragma unroll
        for (int qt = 0; qt < 2; ++qt) {
            f32x4 s2[4];
#pragma unroll
            for (int j = 0; j < 4; ++j) {
                f32x4 z = __builtin_amdgcn_mfma_f32_16x16x32_f16(
                        kf[j][0], aq[qt][0], fz, 0, 0, 0);
                s2[j] = __builtin_amdgcn_mfma_f32_16x16x32_f16(
                        kf[j][1], aq[qt][1], z, 0, 0, 0);
            }

            unsigned int dw[4][2];
#pragma unroll
            for (int j = 0; j < 4; ++j) {
                float p0 = exp2f(fminf(s2[j][0], 15.9f));
                float p1 = exp2f(fminf(s2[j][1], 15.9f));
                float p2 = exp2f(fminf(s2[j][2], 15.9f));
                float p3 = exp2f(fminf(s2[j][3], 15.9f));
                f16x2 h0 = { (f16)p0, (f16)p1 };
                f16x2 h1 = { (f16)p2, (f16)p3 };
                dw[j][0] = __builtin_bit_cast(unsigned int, h0);
                dw[j][1] = __builtin_bit_cast(unsigned int, h1);
            }

            // lane-quarter algebra (matches R8's verified shuffle spec):
            // X=[x0,x1,x2,x3], Y=[y0..y3]; after P32: X=[x0,x1,y0,y1],
            // Y=[x2,x3,y2,y3]; after P16: X=[x0,x2,y0,y2]=O_h0,
            // Y=[x1,x3,y1,y3]=O_h1.  pdw[c][2h+T].
            unsigned int pdw[2][4];
#pragma unroll
            for (int c = 0; c < 2; ++c)
#pragma unroll
                for (int T = 0; T < 2; ++T) {
                    unsigned int X = dw[2 * c][T];
                    unsigned int Y = dw[2 * c + 1][T];
                    asm("v_permlane32_swap_b32 %0, %1" : "+v"(X), "+v"(Y));
                    asm("v_permlane16_swap_b32 %0, %1" : "+v"(X), "+v"(Y));
                    pdw[c][T]     = X;
                    pdw[c][2 + T] = Y;
                }
            union { unsigned int u[4]; f16x8 hv; } cu;
#pragma unroll
            for (int c = 0; c < 2; ++c) {
                cu.u[0] = pdw[c][0]; cu.u[1] = pdw[c][1];
                cu.u[2] = pdw[c][2]; cu.u[3] = pdw[c][3];
                paf[qt][c] = cu.hv;
            }

            // l[q] += sum_k P[q][k]  (lands at lane(grp,fr) reg r = q grp*4+r)
            lacc[qt] = __builtin_amdgcn_mfma_f32_16x16x32_f16(
                paf[qt][0], onesf, lacc[qt], 0, 0, 0);
            lacc[qt] = __builtin_amdgcn_mfma_f32_16x16x32_f16(
                paf[qt][1], onesf, lacc[qt], 0, 0, 0);
        }

        // hoisted V fragments (qt-invariant): V^T[j*16+fr][c*32 + grp*8 + e]
        f16x8 vf[4][2];
#pragma unroll
        for (int j = 0; j < 4; ++j)
#pragma unroll
            for (int c = 0; c < 2; ++c)
                vf[j][c] = *(const f16x8*)&Vs[p][(j * 16 + fr) * 72 + c * 32 + fk8];

#pragma unroll
        for (int qt = 0; qt < 2; ++qt)
#pragma unroll
            for (int j = 0; j < 4; ++j)
#pragma unroll
                for (int c = 0; c < 2; ++c)
                    acc[qt][j] = __builtin_amdgcn_mfma_f32_16x16x32_f16(
                        paf[qt][c], vf[j][c], acc[qt][j], 0, 0, 0);
    }

    // epilogue: every lane already holds l for its own output rows
#pragma unroll
    for (int qt = 0; qt < 2; ++qt) {
        float inv[4];
#pragma unroll
        for (int r = 0; r < 4; ++r) inv[r] = 1.0f / lacc[qt][r];
#pragma unroll
        for (int j = 0; j < 4; ++j)
#pragma unroll
            for (int r = 0; r < 4; ++r) {
                const int q = q0 + wave * 32 + qt * 16 + grp * 4 + r;
                out[(bs + q) * 1536 + h * 64 + j * 16 + fr] =
                    (f16)(acc[qt][j][r] * inv[r]);
            }
    }
}

// ---------------------------------------------------------------------------
// launch
// ---------------------------------------------------------------------------
extern "C" void kernel_launch(void* const* d_in, const int* in_sizes, int n_in,
                              void* d_out, int out_size, void* d_ws, size_t ws_size,
                              hipStream_t stream)
{
    const float* x    = (const float*)d_in[0];   // [16,1024,512]
    const float* Wqkv = (const float*)d_in[1];   // [3,1536,512]
    const float* bqkv = (const float*)d_in[2];   // [3,1536]
    const float* Wo   = (const float*)d_in[3];   // [3,512,512]
    const float* bo   = (const float*)d_in[4];   // [3,512] (flat 1536)
    const float* Wf   = (const float*)d_in[5];   // [512,1536]
    const float* bfin = (const float*)d_in[6];   // [512]
    float* out = (float*)d_out;                  // [16,1024,512] fp32

    char* ws = (char*)d_ws;
    f16*   qkvbuf   = (f16*)ws;                        // 16384x1536 (50,331,648)
    f16*   attn_cat = (f16*)(ws + 50331648);           // 16384x1536 (50,331,648)
    f16*   wfh      = (f16*)(ws + 100663296);          // 512x1536   (1,572,864)
    f16*   WoT      = (f16*)(ws + 102236160);          // 3x512x512  (1,572,864)
    f16*   Wfo      = (f16*)(ws + 103809024);          // 512x1536   (1,572,864)
    float* bp       = (float*)(ws + 105381888);        // 512        (2,048)

    f16* xh    = (f16*)d_out;                          // 8,388,608 el (16.8 MB)
    f16* wqkvh = (f16*)((char*)d_out + 16777216);      // 2,359,296 el (4.7 MB)

    f32_to_f16<<<dim3(4096), 256, 0, stream>>>(x,    xh,    8388608);
    f32_to_f16<<<dim3(1152), 256, 0, stream>>>(Wqkv, wqkvh, 2359296);
    f32_to_f16<<<dim3(384),  256, 0, stream>>>(Wf,   wfh,   786432);
    transpose_wo<<<dim3(16, 16, 3), 256, 0, stream>>>(Wo, WoT);

    // Wfo[z] = Wf[:, 512z:512z+512] @ Wo[z]
    gemm_mfma_nt<f16><<<dim3(4, 4, 3), 256, 0, stream>>>(
        wfh, 1536, 512, WoT, 512, 262144, nullptr, Wfo, 1536, 512, 512);

    // b' = bf + Wf @ bo_flat
    bias_fuse<<<dim3(128), 256, 0, stream>>>(Wf, bo, bfin, bp);

    for (int i = 0; i < 3; ++i) {
        // qkv_i = x @ Wqkv[i]^T + bqkv[i]  -> [16384,1536] f16
        gemm_mfma_nt<f16><<<dim3(12, 128, 1), 256, 0, stream>>>(
            xh, 512, 0, wqkvh + (size_t)i * 786432, 512, 0, bqkv + i * 1536,
            qkvbuf, 1536, 0, 512);

        if (i == 0)
            win_attn_mfma<<<dim3(16, 16, 8), 256, 0, stream>>>(
                qkvbuf, attn_cat + 0 * 512, 5);
        else if (i == 1)
            win_attn_mfma<<<dim3(16, 16, 8), 256, 0, stream>>>(
                qkvbuf, attn_cat + 1 * 512, 10);
        else
            full_attn_mfma<<<dim3(8, 16, 8), 256, 0, stream>>>(
                qkvbuf, attn_cat + 2 * 512);
    }

    // out = attn_cat @ Wfo^T + b'  (fp32 out), M=16384 N=512 K=1536
    gemm_mfma_nt<float><<<dim3(4, 128, 1), 256, 0, stream>>>(
        attn_cat, 1536, 0, Wfo, 1536, 0, bp, out, 512, 0, 1536);
}